// Round 2
// baseline (73.566 us; speedup 1.0000x reference)
//
#include <hip/hip_runtime.h>
#include <hip/hip_bf16.h>
#include <math.h>

#define B_ 4
#define N_ 256
#define M_ 512
#define E_ 256
#define H_ 64

typedef __attribute__((ext_vector_type(8))) short bf16x8;
typedef __attribute__((ext_vector_type(4))) float f32x4;

// tanh-approx gelu: gelu(x) = x * E/(1+E), E = exp2(k1*x + k2*x^3)
__device__ __forceinline__ float gelu_t(float x) {
    float u = x * fmaf(0.1029432f, x * x, 2.3022081f);
    u = fminf(u, 80.0f);
    float E = exp2f(u);
    return x * E * __builtin_amdgcn_rcpf(1.0f + E);
}

// exact (erf) gelu for the FiLM generator path
__device__ __forceinline__ float gelu_e(float x) {
    return 0.5f * x * (1.0f + erff(x * 0.70710678118654752f));
}

// fp32 -> bf16 bits, round-to-nearest-even
__device__ __forceinline__ short f2bf(float f) {
    unsigned u = __float_as_uint(f);
    unsigned r = (u + 0x7FFFu + ((u >> 16) & 1u)) >> 16;
    return (short)r;
}

__global__ void film_kmax_kernel(const float* __restrict__ z,
                                 const float* __restrict__ mu,
                                 unsigned* __restrict__ wsmax) {
    const int total = B_ * N_ * M_;
    int idx = blockIdx.x * blockDim.x + threadIdx.x;
    float mx = 0.0f;
    for (int i = idx; i < total; i += gridDim.x * blockDim.x) {
        int bn = i >> 9;
        int m  = i & (M_ - 1);
        float dz0 = z[2 * m]     - mu[2 * bn];
        float dz1 = z[2 * m + 1] - mu[2 * bn + 1];
        mx = fmaxf(mx, dz0 * dz0 + dz1 * dz1);
    }
    #pragma unroll
    for (int off = 32; off; off >>= 1) mx = fmaxf(mx, __shfl_xor(mx, off, 64));
    __shared__ float sred[4];
    int lane = threadIdx.x & 63, wid = threadIdx.x >> 6;
    if (lane == 0) sred[wid] = mx;
    __syncthreads();
    if (threadIdx.x == 0) {
        float m2 = fmaxf(fmaxf(sred[0], sred[1]), fmaxf(sred[2], sred[3]));
        atomicMax(wsmax, __float_as_uint(m2));
    }
}

// Per-(b,n) FiLM params: par[bn] = { A1[64], A0[64], S[64], T[64] }
//   A1[h] = scale[h]*kn_w0[h]; A0[h] = scale[h]*kn_b0[h]+shift[h]
//   S[g]  = scale[g];          T[g]  = scale[g]*kn_b2[g]+shift[g]
__global__ __launch_bounds__(64) void film_params_kernel(
    const float* __restrict__ emb,
    const float* __restrict__ fg_w1, const float* __restrict__ fg_b1,
    const float* __restrict__ fg_w2, const float* __restrict__ fg_b2,
    const float* __restrict__ kn_w0, const float* __restrict__ kn_b0,
    const float* __restrict__ kn_b2,
    float* __restrict__ par, int sb, int shalf) {
    __shared__ float s_emb[E_];
    __shared__ float s_h[H_];
    const int h = threadIdx.x;
    const int bn = blockIdx.x;

    ((f32x4*)s_emb)[h] = ((const f32x4*)(emb + bn * E_))[h];
    __syncthreads();

    const f32x4* w1r = (const f32x4*)(fg_w1 + h * E_);
    const f32x4* se4 = (const f32x4*)s_emb;
    float acc = fg_b1[h];
    #pragma unroll 8
    for (int e = 0; e < 64; e++) {
        f32x4 w = w1r[e], v = se4[e];
        acc = fmaf(w[0], v[0], fmaf(w[1], v[1], fmaf(w[2], v[2], fmaf(w[3], v[3], acc))));
    }
    s_h[h] = gelu_e(acc);
    __syncthreads();

    const f32x4* wsr = (const f32x4*)(fg_w2 + h * H_);
    const f32x4* whr = (const f32x4*)(fg_w2 + (H_ + h) * H_);
    const f32x4* sh4 = (const f32x4*)s_h;
    float asc = fg_b2[h], ash = fg_b2[H_ + h];
    #pragma unroll
    for (int q = 0; q < 16; q++) {
        f32x4 hv = sh4[q], a = wsr[q], b = whr[q];
        asc = fmaf(a[0], hv[0], fmaf(a[1], hv[1], fmaf(a[2], hv[2], fmaf(a[3], hv[3], asc))));
        ash = fmaf(b[0], hv[0], fmaf(b[1], hv[1], fmaf(b[2], hv[2], fmaf(b[3], hv[3], ash))));
    }
    float A1 = asc * kn_w0[h];
    float A0 = fmaf(asc, kn_b0[h], ash);
    float S  = asc;
    float T  = fmaf(asc, kn_b2[h], ash);
    float* p0 = par + bn * sb;
    p0[h] = A1; p0[H_ + h] = A0; p0[2 * H_ + h] = S; p0[3 * H_ + h] = T;
    if (shalf) {
        float* p1 = p0 + shalf;
        p1[h] = A1; p1[H_ + h] = A0; p1[2 * H_ + h] = S; p1[3 * H_ + h] = T;
    }
}

// grid = 2048: bid -> (bn = bid>>1, half = bid&1); each wave: 64 points (4 tiles of 16)
__global__ __launch_bounds__(256, 3) void film_main_kernel(
    const float* __restrict__ z, const float* __restrict__ mu,
    const float* __restrict__ kn_w2, const float* __restrict__ kn_w4,
    const float* __restrict__ kn_b4,
    const unsigned* __restrict__ wsmax,
    const float* __restrict__ par, int sb, int shalf,
    float* __restrict__ out) {
    const int t = threadIdx.x;
    const int bid = blockIdx.x;
    const int bn = bid >> 1, half = bid & 1;
    const int lane = t & 63, wid = t >> 6;
    const int kg = lane >> 4, cl = lane & 15;

    const float* pb = par + bn * sb + half * shalf;

    // A-side params: h = c*32 + kg*8 + j
    float A1r[16], A0r[16];
    #pragma unroll
    for (int c = 0; c < 2; c++)
        #pragma unroll
        for (int q = 0; q < 2; q++) {
            f32x4 v1 = *(const f32x4*)(pb + c * 32 + kg * 8 + q * 4);
            f32x4 v0 = *(const f32x4*)(pb + 64 + c * 32 + kg * 8 + q * 4);
            #pragma unroll
            for (int i = 0; i < 4; i++) {
                A1r[c * 8 + q * 4 + i] = v1[i];
                A0r[c * 8 + q * 4 + i] = v0[i];
            }
        }
    // epilogue params: g = ct*16 + kg*4 + i
    float Sr[16], Tr[16], w4r[16];
    #pragma unroll
    for (int ct = 0; ct < 4; ct++) {
        f32x4 sv = *(const f32x4*)(pb + 128 + ct * 16 + kg * 4);
        f32x4 tv = *(const f32x4*)(pb + 192 + ct * 16 + kg * 4);
        f32x4 wv = *(const f32x4*)(kn_w4 + ct * 16 + kg * 4);
        #pragma unroll
        for (int i = 0; i < 4; i++) {
            Sr[ct * 4 + i] = sv[i]; Tr[ct * 4 + i] = tv[i]; w4r[ct * 4 + i] = wv[i];
        }
    }
    // A-operand fragments: w2[row g = ct*16+cl][slot h = c*32+kg*8+j]
    bf16x8 bfr[2][4];
    #pragma unroll
    for (int c = 0; c < 2; c++)
        #pragma unroll
        for (int ct = 0; ct < 4; ct++) {
            const float* wr = kn_w2 + (ct * 16 + cl) * H_ + c * 32 + kg * 8;
            f32x4 w0v = *(const f32x4*)(wr);
            f32x4 w1v = *(const f32x4*)(wr + 4);
            bf16x8 v;
            #pragma unroll
            for (int i = 0; i < 4; i++) { v[i] = f2bf(w0v[i]); v[4 + i] = f2bf(w1v[i]); }
            bfr[c][ct] = v;
        }

    float maxd2 = __uint_as_float(*wsmax);
    float invd  = __builtin_amdgcn_rcpf(sqrtf(maxd2) + 1e-8f);
    float mu0 = mu[bn * 2], mu1 = mu[bn * 2 + 1];
    float b4v = kn_b4[0];
    float* outr = out + bn * M_;
    const int mbase = half * 256 + wid * 64;

    // fallback mode (params staged in out): all param reads must precede stores
    __syncthreads();

    #pragma unroll 1
    for (int tile = 0; tile < 4; ++tile) {
        int mb = mbase + tile * 16;
        int m  = mb + cl;
        float dz0 = z[2 * m] - mu0, dz1 = z[2 * m + 1] - mu1;
        float nd = sqrtf(dz0 * dz0 + dz1 * dz1) * invd;

        // B-operand fragments: x0[slot h][col = point cl]
        bf16x8 xf[2];
        #pragma unroll
        for (int c = 0; c < 2; c++) {
            bf16x8 v;
            #pragma unroll
            for (int j = 0; j < 8; j++) {
                float x0 = gelu_t(fmaf(nd, A1r[c * 8 + j], A0r[c * 8 + j]));
                v[j] = f2bf(x0);
            }
            xf[c] = v;
        }

        // D[row g][col point]; lane holds col=cl, rows g = ct*16 + kg*4 + reg
        f32x4 acc[4];
        #pragma unroll
        for (int ct = 0; ct < 4; ct++) {
            f32x4 a = {0.f, 0.f, 0.f, 0.f};
            a = __builtin_amdgcn_mfma_f32_16x16x32_bf16(bfr[0][ct], xf[0], a, 0, 0, 0);
            a = __builtin_amdgcn_mfma_f32_16x16x32_bf16(bfr[1][ct], xf[1], a, 0, 0, 0);
            acc[ct] = a;
        }

        float y = 0.0f;
        #pragma unroll
        for (int ct = 0; ct < 4; ct++)
            #pragma unroll
            for (int i = 0; i < 4; i++)
                y = fmaf(gelu_t(fmaf(Sr[ct * 4 + i], acc[ct][i], Tr[ct * 4 + i])),
                         w4r[ct * 4 + i], y);

        // sum the four kg-group partials (lanes cl, cl+16, cl+32, cl+48)
        y += __shfl_xor(y, 16, 64);
        y += __shfl_xor(y, 32, 64);

        if (lane < 16) {
            float yv = y + b4v;
            float E = exp2f(yv * 1.44269504f);
            outr[mb + lane] = E * __builtin_amdgcn_rcpf(1.0f + E);
        }
    }
}

extern "C" void kernel_launch(void* const* d_in, const int* in_sizes, int n_in,
                              void* d_out, int out_size, void* d_ws, size_t ws_size,
                              hipStream_t stream) {
    const float* z      = (const float*)d_in[0];
    const float* mu     = (const float*)d_in[1];
    const float* emb    = (const float*)d_in[2];
    const float* fg_w1  = (const float*)d_in[3];
    const float* fg_b1  = (const float*)d_in[4];
    const float* fg_w2  = (const float*)d_in[5];
    const float* fg_b2  = (const float*)d_in[6];
    const float* kn_w0  = (const float*)d_in[7];
    const float* kn_b0  = (const float*)d_in[8];
    const float* kn_w2  = (const float*)d_in[9];
    const float* kn_b2  = (const float*)d_in[10];
    const float* kn_w4  = (const float*)d_in[11];
    const float* kn_b4  = (const float*)d_in[12];
    float* out = (float*)d_out;
    unsigned* wsmax = (unsigned*)d_ws;

    // param staging: prefer ws; else stage in out (per-half copy, self-overwritten)
    const size_t need = 256 + (size_t)(B_ * N_) * 256 * sizeof(float);
    float* par; int sb, shalf;
    if (ws_size >= need) {
        par = (float*)((char*)d_ws + 256); sb = 256; shalf = 0;
    } else {
        par = out; sb = 512; shalf = 256;
    }

    hipMemsetAsync(d_ws, 0, 4, stream);
    film_kmax_kernel<<<512, 256, 0, stream>>>(z, mu, wsmax);
    film_params_kernel<<<B_ * N_, 64, 0, stream>>>(
        emb, fg_w1, fg_b1, fg_w2, fg_b2, kn_w0, kn_b0, kn_b2, par, sb, shalf);
    film_main_kernel<<<2 * B_ * N_, 256, 0, stream>>>(
        z, mu, kn_w2, kn_w4, kn_b4, wsmax, par, sb, shalf, out);
}

// Round 3
// 67.085 us; speedup vs baseline: 1.0966x; 1.0966x over previous
//
#include <hip/hip_runtime.h>
#include <hip/hip_bf16.h>
#include <math.h>

#define B_ 4
#define N_ 256
#define M_ 512
#define E_ 256
#define H_ 64

typedef __attribute__((ext_vector_type(8))) short bf16x8;
typedef __attribute__((ext_vector_type(4))) float f32x4;

// tanh-form gelu, division-free via rcp, clamp-free, NaN-safe:
// gelu(x) = x * rcp(1 + exp2(-k1*x - k2*x^3)),  k1=2.3022081, k2=0.1029432
__device__ __forceinline__ float gelu7(float x) {
    float un = x * fmaf(-0.1029432f, x * x, -2.3022081f);
    float E = exp2f(un);
    return x * __builtin_amdgcn_rcpf(1.0f + E);
}

// exact (erf) gelu for the FiLM generator path
__device__ __forceinline__ float gelu_e(float x) {
    return 0.5f * x * (1.0f + erff(x * 0.70710678118654752f));
}

// fp32 -> bf16 bits via native convert (v_cvt_pk_bf16_f32 on gfx950, RNE)
__device__ __forceinline__ short sbf(float f) {
    __bf16 h = (__bf16)f;
    return __builtin_bit_cast(short, h);
}

// Per-(b,n): FiLM params + this bn's distance-max (fused, saves a launch).
// par[bn] = { A1[64], A0[64], S[64], T[64] }
__global__ __launch_bounds__(64) void film_params_kernel(
    const float* __restrict__ z, const float* __restrict__ mu,
    const float* __restrict__ emb,
    const float* __restrict__ fg_w1, const float* __restrict__ fg_b1,
    const float* __restrict__ fg_w2, const float* __restrict__ fg_b2,
    const float* __restrict__ kn_w0, const float* __restrict__ kn_b0,
    const float* __restrict__ kn_b2,
    unsigned* __restrict__ wsmax,
    float* __restrict__ par, int sb, int shalf) {
    __shared__ float s_emb[E_];
    __shared__ float s_h[H_];
    const int h = threadIdx.x;
    const int bn = blockIdx.x;

    ((f32x4*)s_emb)[h] = ((const f32x4*)(emb + bn * E_))[h];

    // ---- fused distance-max over this bn's 512 grid points ----
    float mu0 = mu[bn * 2], mu1 = mu[bn * 2 + 1];
    float mx = 0.0f;
    #pragma unroll
    for (int i = 0; i < 8; i++) {
        int m = h + i * 64;
        float2 zz = ((const float2*)z)[m];
        float d0 = zz.x - mu0, d1 = zz.y - mu1;
        mx = fmaxf(mx, fmaf(d0, d0, d1 * d1));
    }
    #pragma unroll
    for (int off = 32; off; off >>= 1) mx = fmaxf(mx, __shfl_xor(mx, off, 64));
    if (h == 0) atomicMax(wsmax, __float_as_uint(mx));

    __syncthreads();

    const f32x4* w1r = (const f32x4*)(fg_w1 + h * E_);
    const f32x4* se4 = (const f32x4*)s_emb;
    float acc = fg_b1[h];
    #pragma unroll 8
    for (int e = 0; e < 64; e++) {
        f32x4 w = w1r[e], v = se4[e];
        acc = fmaf(w[0], v[0], fmaf(w[1], v[1], fmaf(w[2], v[2], fmaf(w[3], v[3], acc))));
    }
    s_h[h] = gelu_e(acc);
    __syncthreads();

    const f32x4* wsr = (const f32x4*)(fg_w2 + h * H_);
    const f32x4* whr = (const f32x4*)(fg_w2 + (H_ + h) * H_);
    const f32x4* sh4 = (const f32x4*)s_h;
    float asc = fg_b2[h], ash = fg_b2[H_ + h];
    #pragma unroll
    for (int q = 0; q < 16; q++) {
        f32x4 hv = sh4[q], a = wsr[q], b = whr[q];
        asc = fmaf(a[0], hv[0], fmaf(a[1], hv[1], fmaf(a[2], hv[2], fmaf(a[3], hv[3], asc))));
        ash = fmaf(b[0], hv[0], fmaf(b[1], hv[1], fmaf(b[2], hv[2], fmaf(b[3], hv[3], ash))));
    }
    float A1 = asc * kn_w0[h];
    float A0 = fmaf(asc, kn_b0[h], ash);
    float S  = asc;
    float T  = fmaf(asc, kn_b2[h], ash);
    float* p0 = par + bn * sb;
    p0[h] = A1; p0[H_ + h] = A0; p0[2 * H_ + h] = S; p0[3 * H_ + h] = T;
    if (shalf) {
        float* p1 = p0 + shalf;
        p1[h] = A1; p1[H_ + h] = A0; p1[2 * H_ + h] = S; p1[3 * H_ + h] = T;
    }
}

// grid = 2048: bid -> (bn = bid>>1, half = bid&1); each wave: 64 points (4 tiles of 16)
__global__ __launch_bounds__(256, 4) void film_main_kernel(
    const float* __restrict__ z, const float* __restrict__ mu,
    const float* __restrict__ kn_w2, const float* __restrict__ kn_w4,
    const float* __restrict__ kn_b4,
    const unsigned* __restrict__ wsmax,
    const float* __restrict__ par, int sb, int shalf,
    float* __restrict__ out) {
    // s_p: A1[0:64) A0[64:128) S[128:192) T[192:256) w4[256:320)
    __shared__ float s_p[320];
    const int t = threadIdx.x;
    const int bid = blockIdx.x;
    const int bn = bid >> 1, half = bid & 1;
    const int lane = t & 63, wid = t >> 6;
    const int kg = lane >> 4, cl = lane & 15;

    const float* pb = par + bn * sb + half * shalf;
    s_p[t] = pb[t];
    if (t < 64) s_p[256 + t] = kn_w4[t];

    // A-operand fragments in regs: w2[row g = ct*16+cl][slot h = c*32+kg*8+j]
    bf16x8 bfr[2][4];
    #pragma unroll
    for (int c = 0; c < 2; c++)
        #pragma unroll
        for (int ct = 0; ct < 4; ct++) {
            const float* wr = kn_w2 + (ct * 16 + cl) * H_ + c * 32 + kg * 8;
            f32x4 w0v = *(const f32x4*)(wr);
            f32x4 w1v = *(const f32x4*)(wr + 4);
            bf16x8 v;
            #pragma unroll
            for (int i = 0; i < 4; i++) { v[i] = sbf(w0v[i]); v[4 + i] = sbf(w1v[i]); }
            bfr[c][ct] = v;
        }

    float maxd2 = __uint_as_float(*wsmax);
    float invd  = __builtin_amdgcn_rcpf(sqrtf(maxd2) + 1e-8f);
    float mu0 = mu[bn * 2], mu1 = mu[bn * 2 + 1];
    float b4v = kn_b4[0];
    const int mbase = half * 256 + wid * 64;

    __syncthreads();
    const f32x4* p4 = (const f32x4*)s_p;

    float yt[4];
    #pragma unroll
    for (int tile = 0; tile < 4; ++tile) {
        int m = mbase + tile * 16 + cl;
        float2 zz = ((const float2*)z)[m];
        float dz0 = zz.x - mu0, dz1 = zz.y - mu1;
        float nd = sqrtf(fmaf(dz0, dz0, dz1 * dz1)) * invd;

        // B-operand: x0[slot h = c*32+kg*8+j][col = point cl]
        bf16x8 xf[2];
        #pragma unroll
        for (int c = 0; c < 2; c++) {
            int qb = (c * 32 + kg * 8) >> 2;           // f32x4 index
            f32x4 a1a = p4[qb], a1b = p4[qb + 1];
            f32x4 a0a = p4[16 + qb], a0b = p4[16 + qb + 1];
            bf16x8 v;
            #pragma unroll
            for (int i = 0; i < 4; i++) {
                v[i]     = sbf(gelu7(fmaf(nd, a1a[i], a0a[i])));
                v[4 + i] = sbf(gelu7(fmaf(nd, a1b[i], a0b[i])));
            }
            xf[c] = v;
        }

        // D[row g][col point]; lane holds col=cl, rows g = ct*16 + kg*4 + i
        f32x4 acc[4];
        #pragma unroll
        for (int ct = 0; ct < 4; ct++) {
            f32x4 a = {0.f, 0.f, 0.f, 0.f};
            a = __builtin_amdgcn_mfma_f32_16x16x32_bf16(bfr[0][ct], xf[0], a, 0, 0, 0);
            a = __builtin_amdgcn_mfma_f32_16x16x32_bf16(bfr[1][ct], xf[1], a, 0, 0, 0);
            acc[ct] = a;
        }

        float y = 0.0f;
        #pragma unroll
        for (int ct = 0; ct < 4; ct++) {
            f32x4 sv = p4[32 + ct * 4 + kg];
            f32x4 tv = p4[48 + ct * 4 + kg];
            f32x4 wv = p4[64 + ct * 4 + kg];
            #pragma unroll
            for (int i = 0; i < 4; i++) {
                float arg = fmaf(sv[i], acc[ct][i], tv[i]);
                y = fmaf(gelu7(arg), wv[i], y);
            }
        }
        // sum the four kg-group partials
        y += __shfl_xor(y, 16, 64);
        y += __shfl_xor(y, 32, 64);
        yt[tile] = y;
    }

    // lane l stores point mbase + l; its tile index is kg, col is cl
    float yv = (kg == 0) ? yt[0] : (kg == 1) ? yt[1] : (kg == 2) ? yt[2] : yt[3];
    yv += b4v;
    float E = exp2f(yv * -1.44269504f);
    out[bn * M_ + mbase + lane] = __builtin_amdgcn_rcpf(1.0f + E);
}

extern "C" void kernel_launch(void* const* d_in, const int* in_sizes, int n_in,
                              void* d_out, int out_size, void* d_ws, size_t ws_size,
                              hipStream_t stream) {
    const float* z      = (const float*)d_in[0];
    const float* mu     = (const float*)d_in[1];
    const float* emb    = (const float*)d_in[2];
    const float* fg_w1  = (const float*)d_in[3];
    const float* fg_b1  = (const float*)d_in[4];
    const float* fg_w2  = (const float*)d_in[5];
    const float* fg_b2  = (const float*)d_in[6];
    const float* kn_w0  = (const float*)d_in[7];
    const float* kn_b0  = (const float*)d_in[8];
    const float* kn_w2  = (const float*)d_in[9];
    const float* kn_b2  = (const float*)d_in[10];
    const float* kn_w4  = (const float*)d_in[11];
    const float* kn_b4  = (const float*)d_in[12];
    float* out = (float*)d_out;
    unsigned* wsmax = (unsigned*)d_ws;

    // param staging: prefer ws; else stage in out (per-half copy, self-overwritten)
    const size_t need = 256 + (size_t)(B_ * N_) * 256 * sizeof(float);
    float* par; int sb, shalf;
    if (ws_size >= need) {
        par = (float*)((char*)d_ws + 256); sb = 256; shalf = 0;
    } else {
        par = out; sb = 512; shalf = 256;
    }

    hipMemsetAsync(d_ws, 0, 4, stream);
    film_params_kernel<<<B_ * N_, 64, 0, stream>>>(
        z, mu, emb, fg_w1, fg_b1, fg_w2, fg_b2, kn_w0, kn_b0, kn_b2,
        wsmax, par, sb, shalf);
    film_main_kernel<<<2 * B_ * N_, 256, 0, stream>>>(
        z, mu, kn_w2, kn_w4, kn_b4, wsmax, par, sb, shalf, out);
}

// Round 4
// 63.919 us; speedup vs baseline: 1.1509x; 1.0495x over previous
//
#include <hip/hip_runtime.h>
#include <hip/hip_bf16.h>
#include <math.h>

#define B_ 4
#define N_ 256
#define M_ 512
#define E_ 256
#define H_ 64

typedef __attribute__((ext_vector_type(8))) short bf16x8;
typedef __attribute__((ext_vector_type(4))) float f32x4;

// tanh-form gelu, division-free, clamp-free, NaN-safe:
// gelu(x) = x * rcp(1 + exp2(-k1*x - k2*x^3)),  k1=2.3022081, k2=0.1029432
__device__ __forceinline__ float gelu7(float x) {
    float un = x * fmaf(-0.1029432f, x * x, -2.3022081f);
    float E = exp2f(un);
    return x * __builtin_amdgcn_rcpf(1.0f + E);
}

// exact (erf) gelu for the FiLM generator path
__device__ __forceinline__ float gelu_e(float x) {
    return 0.5f * x * (1.0f + erff(x * 0.70710678118654752f));
}

// fp32 -> bf16 bits via native convert (RNE)
__device__ __forceinline__ short sbf(float f) {
    __bf16 h = (__bf16)f;
    return __builtin_bit_cast(short, h);
}

// Per-(b,n): FiLM params + per-bn distance max. 256 threads, phases split.
// par[bn] = { A1[64], A0[64], S[64], T[64] }
__global__ __launch_bounds__(256) void film_params_kernel(
    const float* __restrict__ z, const float* __restrict__ mu,
    const float* __restrict__ emb,
    const float* __restrict__ fg_w1, const float* __restrict__ fg_b1,
    const float* __restrict__ fg_w2, const float* __restrict__ fg_b2,
    const float* __restrict__ kn_w0, const float* __restrict__ kn_b0,
    const float* __restrict__ kn_b2,
    unsigned* __restrict__ wsmax,
    float* __restrict__ par, int sb, int shalf) {
    __shared__ float s_emb[E_];
    __shared__ float s_part[256];
    __shared__ float s_h[H_];
    __shared__ float s_sc[H_], s_sh[H_];
    __shared__ float s_mx[4];
    const int t = threadIdx.x;
    const int bn = blockIdx.x;

    s_emb[t] = emb[bn * E_ + t];

    // distance max: 2 points per thread
    float mu0 = mu[2 * bn], mu1 = mu[2 * bn + 1];
    float2 z0 = ((const float2*)z)[t];
    float2 z1 = ((const float2*)z)[t + 256];
    float d0 = z0.x - mu0, d1 = z0.y - mu1;
    float mx = fmaf(d0, d0, d1 * d1);
    d0 = z1.x - mu0; d1 = z1.y - mu1;
    mx = fmaxf(mx, fmaf(d0, d0, d1 * d1));
    #pragma unroll
    for (int off = 32; off; off >>= 1) mx = fmaxf(mx, __shfl_xor(mx, off, 64));
    if ((t & 63) == 0) s_mx[t >> 6] = mx;
    __syncthreads();
    if (t == 0)
        atomicMax(wsmax, __float_as_uint(
            fmaxf(fmaxf(s_mx[0], s_mx[1]), fmaxf(s_mx[2], s_mx[3]))));

    // phase A: partial w1 dots — thread (h = t&63, q = t>>6) does 64 MACs
    {
        int h = t & 63, q = t >> 6;
        const f32x4* wr = (const f32x4*)(fg_w1 + h * E_ + q * 64);
        const f32x4* er = (const f32x4*)(s_emb + q * 64);
        float acc = 0.0f;
        #pragma unroll
        for (int e = 0; e < 16; e++) {
            f32x4 w = wr[e], v = er[e];
            acc = fmaf(w[0], v[0], fmaf(w[1], v[1], fmaf(w[2], v[2], fmaf(w[3], v[3], acc))));
        }
        s_part[t] = acc;
    }
    __syncthreads();
    if (t < H_) {
        float hv = s_part[t] + s_part[64 + t] + s_part[128 + t] + s_part[192 + t] + fg_b1[t];
        s_h[t] = gelu_e(hv);
    }
    __syncthreads();
    // phase C: g = t>>1 (0..127), hf = t&1 — 32 MACs each, pair-combine via shfl
    {
        int g = t >> 1, hf = t & 1;
        const f32x4* wr = (const f32x4*)(fg_w2 + g * H_ + hf * 32);
        const f32x4* hr = (const f32x4*)(s_h + hf * 32);
        float acc = 0.0f;
        #pragma unroll
        for (int q = 0; q < 8; q++) {
            f32x4 w = wr[q], v = hr[q];
            acc = fmaf(w[0], v[0], fmaf(w[1], v[1], fmaf(w[2], v[2], fmaf(w[3], v[3], acc))));
        }
        acc += __shfl_xor(acc, 1, 64);
        if (!hf) {
            float val = acc + fg_b2[g];
            if (g < H_) s_sc[g] = val; else s_sh[g - H_] = val;
        }
    }
    __syncthreads();
    if (t < H_) {
        float sc = s_sc[t], sh = s_sh[t];
        float A1 = sc * kn_w0[t];
        float A0 = fmaf(sc, kn_b0[t], sh);
        float S  = sc;
        float T  = fmaf(sc, kn_b2[t], sh);
        float* p0 = par + bn * sb;
        p0[t] = A1; p0[H_ + t] = A0; p0[2 * H_ + t] = S; p0[3 * H_ + t] = T;
        if (shalf) {
            float* p1 = p0 + shalf;
            p1[t] = A1; p1[H_ + t] = A0; p1[2 * H_ + t] = S; p1[3 * H_ + t] = T;
        }
    }
}

// grid = 2048: bid -> (bn = bid>>1, half = bid&1); each wave: 64 points (4 tiles of 16)
// All per-block params register-pinned; zero in-loop memory traffic.
__global__ __launch_bounds__(256, 2) void film_main_kernel(
    const float* __restrict__ z, const float* __restrict__ mu,
    const float* __restrict__ kn_w2, const float* __restrict__ kn_w4,
    const float* __restrict__ kn_b4,
    const unsigned* __restrict__ wsmax,
    const float* __restrict__ par, int sb, int shalf,
    float* __restrict__ out) {
    const int t = threadIdx.x;
    const int bid = blockIdx.x;
    const int bn = bid >> 1, half = bid & 1;
    const int lane = t & 63, wid = t >> 6;
    const int kg = lane >> 4, cl = lane & 15;
    const float* pb = par + bn * sb + half * shalf;
    const int mbase = half * 256 + wid * 64;

    // z for all 4 tiles, issued early
    float2 zz[4];
    #pragma unroll
    for (int tl = 0; tl < 4; tl++) zz[tl] = ((const float2*)z)[mbase + tl * 16 + cl];

    // A-side params: h = c*32 + kg*8 + q*4 + i
    f32x4 A1v[4], A0v[4];
    #pragma unroll
    for (int c = 0; c < 2; c++) {
        #pragma unroll
        for (int q = 0; q < 2; q++) {
            A1v[c * 2 + q] = *(const f32x4*)(pb + c * 32 + kg * 8 + q * 4);
            A0v[c * 2 + q] = *(const f32x4*)(pb + 64 + c * 32 + kg * 8 + q * 4);
        }
    }
    // epilogue params: g = ct*16 + kg*4 + i
    f32x4 Sv[4], Tv[4], Wv[4];
    #pragma unroll
    for (int ct = 0; ct < 4; ct++) {
        Sv[ct] = *(const f32x4*)(pb + 128 + ct * 16 + kg * 4);
        Tv[ct] = *(const f32x4*)(pb + 192 + ct * 16 + kg * 4);
        Wv[ct] = *(const f32x4*)(kn_w4 + ct * 16 + kg * 4);
    }
    // w2 fragments: w2[row g = ct*16+cl][slot h = c*32+kg*8+j]
    bf16x8 bfr[2][4];
    #pragma unroll
    for (int c = 0; c < 2; c++) {
        #pragma unroll
        for (int ct = 0; ct < 4; ct++) {
            const float* wr = kn_w2 + (ct * 16 + cl) * H_ + c * 32 + kg * 8;
            f32x4 w0v = *(const f32x4*)(wr);
            f32x4 w1v = *(const f32x4*)(wr + 4);
            bf16x8 v;
            #pragma unroll
            for (int i = 0; i < 4; i++) { v[i] = sbf(w0v[i]); v[4 + i] = sbf(w1v[i]); }
            bfr[c][ct] = v;
        }
    }

    float maxd2 = __uint_as_float(*wsmax);
    float invd  = __builtin_amdgcn_rcpf(sqrtf(maxd2) + 1e-8f);
    float mu0 = mu[bn * 2], mu1 = mu[bn * 2 + 1];
    float b4v = kn_b4[0];

    // pin params in registers — forbid remat-from-memory inside the loop
    asm volatile("" : "+v"(A1v[0]), "+v"(A1v[1]), "+v"(A1v[2]), "+v"(A1v[3]),
                      "+v"(A0v[0]), "+v"(A0v[1]), "+v"(A0v[2]), "+v"(A0v[3]));
    asm volatile("" : "+v"(Sv[0]), "+v"(Sv[1]), "+v"(Sv[2]), "+v"(Sv[3]),
                      "+v"(Tv[0]), "+v"(Tv[1]), "+v"(Tv[2]), "+v"(Tv[3]));
    asm volatile("" : "+v"(Wv[0]), "+v"(Wv[1]), "+v"(Wv[2]), "+v"(Wv[3]));

    // fallback mode (params staged in out): param reads must precede stores
    __syncthreads();

    float yt[4];
    #pragma unroll
    for (int tl = 0; tl < 4; tl++) {
        float dz0 = zz[tl].x - mu0, dz1 = zz[tl].y - mu1;
        float nd = sqrtf(fmaf(dz0, dz0, dz1 * dz1)) * invd;

        // B-operand: x0[slot h][col = point cl]
        bf16x8 xf[2];
        #pragma unroll
        for (int c = 0; c < 2; c++) {
            bf16x8 v;
            #pragma unroll
            for (int q = 0; q < 2; q++) {
                f32x4 a1 = A1v[c * 2 + q], a0 = A0v[c * 2 + q];
                #pragma unroll
                for (int i = 0; i < 4; i++)
                    v[q * 4 + i] = sbf(gelu7(fmaf(nd, a1[i], a0[i])));
            }
            xf[c] = v;
        }

        // D[row g][col point]; lane holds col=cl, rows g = ct*16 + kg*4 + i
        f32x4 acc[4];
        #pragma unroll
        for (int ct = 0; ct < 4; ct++) {
            f32x4 a = {0.f, 0.f, 0.f, 0.f};
            a = __builtin_amdgcn_mfma_f32_16x16x32_bf16(bfr[0][ct], xf[0], a, 0, 0, 0);
            a = __builtin_amdgcn_mfma_f32_16x16x32_bf16(bfr[1][ct], xf[1], a, 0, 0, 0);
            acc[ct] = a;
        }

        float ya = 0.0f, yb = 0.0f;
        #pragma unroll
        for (int ct = 0; ct < 4; ct++) {
            f32x4 sv = Sv[ct], tv = Tv[ct], wv = Wv[ct];
            ya = fmaf(gelu7(fmaf(sv[0], acc[ct][0], tv[0])), wv[0], ya);
            yb = fmaf(gelu7(fmaf(sv[1], acc[ct][1], tv[1])), wv[1], yb);
            ya = fmaf(gelu7(fmaf(sv[2], acc[ct][2], tv[2])), wv[2], ya);
            yb = fmaf(gelu7(fmaf(sv[3], acc[ct][3], tv[3])), wv[3], yb);
        }
        float y = ya + yb;
        y += __shfl_xor(y, 16, 64);
        y += __shfl_xor(y, 32, 64);
        yt[tl] = y;
    }

    // lane l stores point mbase + l; its tile index is kg, col is cl
    float yv = (kg == 0) ? yt[0] : (kg == 1) ? yt[1] : (kg == 2) ? yt[2] : yt[3];
    yv += b4v;
    float E = exp2f(yv * -1.44269504f);
    out[bn * M_ + mbase + lane] = __builtin_amdgcn_rcpf(1.0f + E);
}

extern "C" void kernel_launch(void* const* d_in, const int* in_sizes, int n_in,
                              void* d_out, int out_size, void* d_ws, size_t ws_size,
                              hipStream_t stream) {
    const float* z      = (const float*)d_in[0];
    const float* mu     = (const float*)d_in[1];
    const float* emb    = (const float*)d_in[2];
    const float* fg_w1  = (const float*)d_in[3];
    const float* fg_b1  = (const float*)d_in[4];
    const float* fg_w2  = (const float*)d_in[5];
    const float* fg_b2  = (const float*)d_in[6];
    const float* kn_w0  = (const float*)d_in[7];
    const float* kn_b0  = (const float*)d_in[8];
    const float* kn_w2  = (const float*)d_in[9];
    const float* kn_b2  = (const float*)d_in[10];
    const float* kn_w4  = (const float*)d_in[11];
    const float* kn_b4  = (const float*)d_in[12];
    float* out = (float*)d_out;
    unsigned* wsmax = (unsigned*)d_ws;

    // param staging: prefer ws; else stage in out (per-half copy, self-overwritten)
    const size_t need = 256 + (size_t)(B_ * N_) * 256 * sizeof(float);
    float* par; int sb, shalf;
    if (ws_size >= need) {
        par = (float*)((char*)d_ws + 256); sb = 256; shalf = 0;
    } else {
        par = out; sb = 512; shalf = 256;
    }

    hipMemsetAsync(d_ws, 0, 4, stream);
    film_params_kernel<<<B_ * N_, 256, 0, stream>>>(
        z, mu, emb, fg_w1, fg_b1, fg_w2, fg_b2, kn_w0, kn_b0, kn_b2,
        wsmax, par, sb, shalf);
    film_main_kernel<<<2 * B_ * N_, 256, 0, stream>>>(
        z, mu, kn_w2, kn_w4, kn_b4, wsmax, par, sb, shalf, out);
}